// Round 5
// baseline (736.444 us; speedup 1.0000x reference)
//
#include <hip/hip_runtime.h>
#include <math.h>

typedef unsigned short u16;
typedef __bf16 bf16x8 __attribute__((ext_vector_type(8)));
typedef float f32x4 __attribute__((ext_vector_type(4)));
typedef unsigned short u16x8 __attribute__((ext_vector_type(8)));
typedef unsigned short u16x4 __attribute__((ext_vector_type(4)));

#define H 2048
#define LSEQ 1024
#define LP (LSEQ+3)
#define CL 32
#define NCH 32

__device__ __forceinline__ float bf2f(u16 u) {
    union { float f; unsigned int i; } x; x.i = ((unsigned int)u) << 16; return x.f;
}
__device__ __forceinline__ u16 f2bf(float f) {
    union { float f; unsigned int i; } x; x.f = f;
    unsigned int r = x.i + 0x7fffu + ((x.i >> 16) & 1u);
    return (u16)(r >> 16);
}

__device__ __forceinline__ void gload_lds16(const void* g, void* l) {
    __builtin_amdgcn_global_load_lds((const __attribute__((address_space(1))) void*)g,
                                     (__attribute__((address_space(3))) void*)l,
                                     16, 0, 0);
}

enum { EPI_XZ = 0, EPI_CONV = 1, EPI_DBC = 2, EPI_OUT = 3, EPI_DELTA = 4 };

// C[m,n] = sum_tap A_tap[m,:] . B_tap[n,:]   (A,B bf16, K-contiguous, row stride K)
template<int EPI, int NTAP>
__launch_bounds__(256)
__global__ void gemm_bt(const u16* __restrict__ A, const u16* __restrict__ B,
                        int K, long aTapStride, long bTapStride,
                        void* __restrict__ out0, void* __restrict__ out1,
                        const float* __restrict__ bias, const float* __restrict__ resid) {
    __shared__ u16 As[128 * 32];
    __shared__ u16 Bs[128 * 32];
    const int m0 = blockIdx.x * 128;
    const int n0 = blockIdx.y * 128;
    const int tid = threadIdx.x;
    const int lane = tid & 63;
    const int w = tid >> 6;
    const int wr = w >> 1, wc = w & 1;
    const int scol = (tid & 3) * 8;

    long abase;
    if (EPI == EPI_CONV) {
        int b = m0 >> 10, l0 = m0 & 1023;
        abase = (long)(b * LP + l0) * K;
    } else {
        abase = (long)m0 * K;
    }
    const u16* Bt = B + (long)n0 * K;

    f32x4 acc[4][4];
#pragma unroll
    for (int i = 0; i < 4; i++)
#pragma unroll
        for (int j = 0; j < 4; j++) acc[i][j] = (f32x4){0.f, 0.f, 0.f, 0.f};

    const int kIters = K / 32;
    for (int tap = 0; tap < NTAP; ++tap) {
        const u16* Ag = A + abase + (long)tap * aTapStride;
        const u16* Bg = Bt + (long)tap * bTapStride;
        for (int kt = 0; kt < kIters; ++kt) {
            const int k0 = kt * 32;
            __syncthreads();
#pragma unroll
            for (int j = 0; j < 2; j++) {
                const int idx = j * 256 + tid;
                const int r = idx >> 2;
                gload_lds16(Ag + (long)r * K + k0 + scol, &As[idx * 8]);
                gload_lds16(Bg + (long)r * K + k0 + scol, &Bs[idx * 8]);
            }
            __syncthreads();
            bf16x8 af[4], bfr[4];
#pragma unroll
            for (int i = 0; i < 4; i++) {
                const int row = wr * 64 + i * 16 + (lane & 15);
                af[i] = *(const bf16x8*)&As[row * 32 + (lane >> 4) * 8];
            }
#pragma unroll
            for (int j = 0; j < 4; j++) {
                const int row = wc * 64 + j * 16 + (lane & 15);
                bfr[j] = *(const bf16x8*)&Bs[row * 32 + (lane >> 4) * 8];
            }
#pragma unroll
            for (int i = 0; i < 4; i++)
#pragma unroll
                for (int j = 0; j < 4; j++)
                    acc[i][j] = __builtin_amdgcn_mfma_f32_16x16x32_bf16(af[i], bfr[j], acc[i][j], 0, 0, 0);
        }
    }

#pragma unroll
    for (int i = 0; i < 4; i++) {
#pragma unroll
        for (int j = 0; j < 4; j++) {
#pragma unroll
            for (int r = 0; r < 4; r++) {
                const int m = m0 + wr * 64 + i * 16 + ((lane >> 4) << 2) + r;
                const int n = n0 + wc * 64 + j * 16 + (lane & 15);
                float v = acc[i][j][r];
                if constexpr (EPI == EPI_XZ) {
                    const int b = m >> 10, l = m & 1023;
                    if (n < H) ((u16*)out0)[((long)(b * LP + l + 3)) * H + n] = f2bf(v);
                    else       ((u16*)out1)[(long)m * H + (n - H)] = f2bf(v);
                } else if constexpr (EPI == EPI_CONV) {
                    v += bias[n];
                    v = v / (1.f + expf(-v));   // silu
                    ((u16*)out0)[(long)m * H + n] = f2bf(v);
                } else if constexpr (EPI == EPI_DBC) {
                    if (n < 96) ((float*)out0)[(long)m * 96 + n] = v;
                    if (n < 64) ((u16*)out1)[(long)m * 64 + n] = f2bf(v);
                } else if constexpr (EPI == EPI_DELTA) {
                    v += bias[n];
                    v = (v > 20.f) ? v : log1pf(expf(v));   // softplus
                    ((float*)out0)[(long)m * H + n] = v;
                } else {
                    ((float*)out0)[(long)m * H + n] = v + resid[(long)m * H + n];
                }
            }
        }
    }
}

// conv_w (tap,i,o) fp32 -> Wt (tap,o,i) bf16
__global__ void transpose_w(const float* __restrict__ in, u16* __restrict__ out) {
    __shared__ u16 s[64][72];
    const int tap = blockIdx.z;
    const long base = (long)tap * H * H;
    const int i0 = blockIdx.x * 64, o0 = blockIdx.y * 64;
    const int r = threadIdx.x >> 3;
    const int c = (threadIdx.x & 7) * 8;
#pragma unroll
    for (int rr = r; rr < 64; rr += 32) {
        f32x4 a = *(const f32x4*)&in[base + (long)(i0 + rr) * H + o0 + c];
        f32x4 b = *(const f32x4*)&in[base + (long)(i0 + rr) * H + o0 + c + 4];
#pragma unroll
        for (int j = 0; j < 4; j++) { s[rr][c + j] = f2bf(a[j]); s[rr][c + 4 + j] = f2bf(b[j]); }
    }
    __syncthreads();
#pragma unroll
    for (int rr = r; rr < 64; rr += 32) {
        u16x8 v;
#pragma unroll
        for (int j = 0; j < 8; j++) v[j] = s[c + j][rr];
        *(u16x8*)&out[base + (long)(o0 + rr) * H + i0 + c] = v;
    }
}

__global__ void cast_f2b_k(const float* __restrict__ in, u16* __restrict__ out) {
    const long i = ((long)blockIdx.x * 256 + threadIdx.x) * 4;
    f32x4 v = *(const f32x4*)(in + i);
    u16x4 o;
#pragma unroll
    for (int j = 0; j < 4; j++) o[j] = f2bf(v[j]);
    *(u16x4*)(out + i) = o;
}

__global__ void pad_zero_k(u16* __restrict__ xcp) {
    const int i = blockIdx.x * 256 + threadIdx.x;   // 2*3*H total
    const int b = i / (3 * H);
    const int r = i - b * 3 * H;
    xcp[(long)b * LP * H + r] = 0;
}

__global__ void xpw_k(const float* __restrict__ xp, u16* __restrict__ out) {
    const int i = blockIdx.x * 256 + threadIdx.x;   // 128*H
    const int r = i >> 11;
    out[i] = (r < 96) ? f2bf(xp[i]) : (u16)0;
}

__global__ void rmsnorm_k(const float* __restrict__ x, const float* __restrict__ w, u16* __restrict__ h) {
    const long base = (long)blockIdx.x * H;
    const int tid = threadIdx.x;
    f32x4 a = *(const f32x4*)&x[base + tid * 8];
    f32x4 b = *(const f32x4*)&x[base + tid * 8 + 4];
    float f[8];
    float ss = 0.f;
#pragma unroll
    for (int j = 0; j < 4; j++) { f[j] = a[j]; f[4 + j] = b[j]; }
#pragma unroll
    for (int j = 0; j < 8; j++) ss += f[j] * f[j];
#pragma unroll
    for (int m = 32; m > 0; m >>= 1) ss += __shfl_down(ss, m);
    __shared__ float red[4];
    if ((tid & 63) == 0) red[tid >> 6] = ss;
    __syncthreads();
    ss = red[0] + red[1] + red[2] + red[3];
    const float scale = rsqrtf(ss * (1.f / H) + 1e-5f);
    f32x4 wa = *(const f32x4*)&w[tid * 8];
    f32x4 wb = *(const f32x4*)&w[tid * 8 + 4];
    u16x8 o;
#pragma unroll
    for (int j = 0; j < 4; j++) { o[j] = f2bf(f[j] * scale * wa[j]); o[4 + j] = f2bf(f[4 + j] * scale * wb[j]); }
    *(u16x8*)&h[base + tid * 8] = o;
}

// ---------- chunked scan, channel-per-thread ----------
// pass1: per (b,chunk,h) local scan of CL steps over 16 in-register states.
// Exploits A[h,n] = -(n+1) (verified at runtime): e_n = e1^(n+1), e1 = exp(-delta).
// Writes bf16 chunk-final states + sum(delta) (exact chunk decay via exp(A*sum)).
__launch_bounds__(256)
__global__ void scan_part1(const float* __restrict__ delta, const u16* __restrict__ xc,
                           const float* __restrict__ dbc, const float* __restrict__ alog,
                           u16* __restrict__ ssum, float* __restrict__ sdl_buf) {
    __shared__ float sB[CL * 16];
    const int tid = threadIdx.x;
    const int bc = blockIdx.x;          // b*NCH + c
    const int b = bc >> 5, c = bc & 31;
    const int h = blockIdx.y * 256 + tid;
    const long tok0 = (long)b * LSEQ + c * CL;
    {
        const int r = tid >> 4, n = tid & 15;
        sB[tid] = dbc[(tok0 + r) * 96 + 64 + n];
        sB[tid + 256] = dbc[(tok0 + r + 16) * 96 + 64 + n];
    }
    __syncthreads();
    float An[16]; bool fast = true;
#pragma unroll
    for (int n = 0; n < 16; n++) {
        An[n] = -expf(alog[h * 16 + n]);
        fast = fast && (fabsf(An[n] + (float)(n + 1)) < 1e-3f * (n + 1));
    }
    float s[16];
#pragma unroll
    for (int n = 0; n < 16; n++) s[n] = 0.f;
    float sdl = 0.f;
    const float* dptr = delta + tok0 * H + h;
    const u16* xptr = xc + tok0 * H + h;
    float dl = dptr[0], xv = bf2f(xptr[0]);
    if (fast) {
        for (int j = 0; j < CL; j++) {
            const long jn = (j < CL - 1) ? (long)(j + 1) * H : (long)j * H;
            const float dl2 = dptr[jn]; const float xv2 = bf2f(xptr[jn]);
            sdl += dl;
            const float e1 = expf(-dl);
            const float u = dl * xv;
            const f32x4* Bv = (const f32x4*)&sB[j * 16];
            float ep = 1.f;
#pragma unroll
            for (int q = 0; q < 4; q++) {
                const f32x4 bb = Bv[q];
#pragma unroll
                for (int k = 0; k < 4; k++) { ep *= e1; s[q*4+k] = ep * s[q*4+k] + u * bb[k]; }
            }
            dl = dl2; xv = xv2;
        }
    } else {
        for (int j = 0; j < CL; j++) {
            const long jn = (j < CL - 1) ? (long)(j + 1) * H : (long)j * H;
            const float dl2 = dptr[jn]; const float xv2 = bf2f(xptr[jn]);
            sdl += dl;
            const float u = dl * xv;
            const f32x4* Bv = (const f32x4*)&sB[j * 16];
#pragma unroll
            for (int q = 0; q < 4; q++) {
                const f32x4 bb = Bv[q];
#pragma unroll
                for (int k = 0; k < 4; k++) { const float e = expf(dl * An[q*4+k]); s[q*4+k] = e * s[q*4+k] + u * bb[k]; }
            }
            dl = dl2; xv = xv2;
        }
    }
    u16x8 o0, o1;
#pragma unroll
    for (int n = 0; n < 8; n++) { o0[n] = f2bf(s[n]); o1[n] = f2bf(s[8 + n]); }
    const long sb = ((long)bc * H + h) * 16;
    *(u16x8*)&ssum[sb] = o0;
    *(u16x8*)&ssum[sb + 8] = o1;
    sdl_buf[(long)bc * H + h] = sdl;
}

// pass2: per (b,h,n) scan over NCH chunk summaries; replaces local state with entering prefix.
__global__ void scan_mid(u16* __restrict__ ssum, const float* __restrict__ sdl_buf,
                         const float* __restrict__ alog) {
    const int tg = blockIdx.x * 256 + threadIdx.x;   // b*(H*16) + h*16 + n
    const int b = tg >> 15;
    const int rest = tg & 32767;
    const int h = rest >> 4, n = rest & 15;
    const float An = -expf(alog[h * 16 + n]);
    float S = 0.f;
    for (int c = 0; c < NCH; c++) {
        const long base = (long)(b * NCH + c) * H + h;
        const float a = expf(An * sdl_buf[base]);
        const long si = base * 16 + n;
        const float sloc = bf2f(ssum[si]);
        ssum[si] = f2bf(S);
        S = a * S + sloc;
    }
}

// pass3: re-scan from prefix, fuse y = (sum_n s*C + D*x) * silu(z), coalesced output.
__launch_bounds__(256)
__global__ void scan_part3(const float* __restrict__ delta, const u16* __restrict__ xc,
                           const float* __restrict__ dbc, const float* __restrict__ alog,
                           const float* __restrict__ dvec, const u16* __restrict__ z,
                           const u16* __restrict__ ssum, u16* __restrict__ ybuf) {
    __shared__ float sB[CL * 16];
    __shared__ float sC[CL * 16];
    const int tid = threadIdx.x;
    const int bc = blockIdx.x;
    const int b = bc >> 5, c = bc & 31;
    const int h = blockIdx.y * 256 + tid;
    const long tok0 = (long)b * LSEQ + c * CL;
    {
        const int r = tid >> 4, n = tid & 15;
        sB[tid]       = dbc[(tok0 + r) * 96 + 64 + n];
        sB[tid + 256] = dbc[(tok0 + r + 16) * 96 + 64 + n];
        sC[tid]       = dbc[(tok0 + r) * 96 + 80 + n];
        sC[tid + 256] = dbc[(tok0 + r + 16) * 96 + 80 + n];
    }
    __syncthreads();
    float An[16]; bool fast = true;
#pragma unroll
    for (int n = 0; n < 16; n++) {
        An[n] = -expf(alog[h * 16 + n]);
        fast = fast && (fabsf(An[n] + (float)(n + 1)) < 1e-3f * (n + 1));
    }
    float s[16];
    {
        const long sb = ((long)bc * H + h) * 16;
        u16x8 i0 = *(const u16x8*)&ssum[sb];
        u16x8 i1 = *(const u16x8*)&ssum[sb + 8];
#pragma unroll
        for (int n = 0; n < 8; n++) { s[n] = bf2f(i0[n]); s[8 + n] = bf2f(i1[n]); }
    }
    const float Dh = dvec[h];
    const float* dptr = delta + tok0 * H + h;
    const u16* xptr = xc + tok0 * H + h;
    const u16* zptr = z + tok0 * H + h;
    u16* yptr = ybuf + tok0 * H + h;
    float dl = dptr[0], xv = bf2f(xptr[0]), zf = bf2f(zptr[0]);
    if (fast) {
        for (int j = 0; j < CL; j++) {
            const long jn = (j < CL - 1) ? (long)(j + 1) * H : (long)j * H;
            const float dl2 = dptr[jn]; const float xv2 = bf2f(xptr[jn]); const float zf2 = bf2f(zptr[jn]);
            const float e1 = expf(-dl);
            const float u = dl * xv;
            const f32x4* Bv = (const f32x4*)&sB[j * 16];
            const f32x4* Cv = (const f32x4*)&sC[j * 16];
            float ep = 1.f, y = 0.f;
#pragma unroll
            for (int q = 0; q < 4; q++) {
                const f32x4 bb = Bv[q], cc = Cv[q];
#pragma unroll
                for (int k = 0; k < 4; k++) {
                    ep *= e1;
                    s[q*4+k] = ep * s[q*4+k] + u * bb[k];
                    y += s[q*4+k] * cc[k];
                }
            }
            y += Dh * xv;
            const float g = zf / (1.f + expf(-zf));
            yptr[(long)j * H] = f2bf(y * g);
            dl = dl2; xv = xv2; zf = zf2;
        }
    } else {
        for (int j = 0; j < CL; j++) {
            const long jn = (j < CL - 1) ? (long)(j + 1) * H : (long)j * H;
            const float dl2 = dptr[jn]; const float xv2 = bf2f(xptr[jn]); const float zf2 = bf2f(zptr[jn]);
            const float u = dl * xv;
            const f32x4* Bv = (const f32x4*)&sB[j * 16];
            const f32x4* Cv = (const f32x4*)&sC[j * 16];
            float y = 0.f;
#pragma unroll
            for (int q = 0; q < 4; q++) {
                const f32x4 bb = Bv[q], cc = Cv[q];
#pragma unroll
                for (int k = 0; k < 4; k++) {
                    const float e = expf(dl * An[q*4+k]);
                    s[q*4+k] = e * s[q*4+k] + u * bb[k];
                    y += s[q*4+k] * cc[k];
                }
            }
            y += Dh * xv;
            const float g = zf / (1.f + expf(-zf));
            yptr[(long)j * H] = f2bf(y * g);
            dl = dl2; xv = xv2; zf = zf2;
        }
    }
}

extern "C" void kernel_launch(void* const* d_in, const int* in_sizes, int n_in,
                              void* d_out, int out_size, void* d_ws, size_t ws_size,
                              hipStream_t stream) {
    const float* x       = (const float*)d_in[0];
    const float* norm_w  = (const float*)d_in[1];
    const float* in_proj = (const float*)d_in[2];
    const float* conv_w  = (const float*)d_in[3];
    const float* conv_b  = (const float*)d_in[4];
    const float* x_proj  = (const float*)d_in[5];
    const float* dt_w    = (const float*)d_in[6];
    const float* dt_b    = (const float*)d_in[7];
    const float* a_log   = (const float*)d_in[8];
    const float* Dv      = (const float*)d_in[9];
    const float* out_w   = (const float*)d_in[10];
    float* out = (float*)d_out;

    char* ws = (char*)d_ws;
    u16*   xcp    = (u16*)(ws);                   //  8,413,184  padded conv input (bf16)
    u16*   hy     = (u16*)(ws + 8413184);         //  8,388,608  h -> xcc
    u16*   z_buf  = (u16*)(ws + 16801792);        //  8,388,608
    u16*   wt     = (u16*)(ws + 25190400);        // 33,554,432  conv_w^T bf16 (dead after conv)
    float* dlt    = (float*)(ws + 25190400);      // 16,777,216  aliases wt (after conv)
    u16*   y_buf  = (u16*)(ws + 41967616);        //  8,388,608  aliases wt
    u16*   ssum   = (u16*)(ws + 50356224);        //  8,388,608  chunk states (aliases wt tail)
    u16*   inw    = (u16*)(ws + 58744832);        // 16,777,216  in_proj bf16 (dead after XZ)
    u16*   outw   = (u16*)(ws + 58744832);        //  8,388,608  out_proj bf16
    float* sdl    = (float*)(ws + 67133440);      //    524,288  per-chunk sum(delta) (inw tail)
    u16*   xpw    = (u16*)(ws + 75522048);        //    524,288  x_proj bf16 padded
    float* dbc    = (float*)(ws + 76046336);      //    786,432  fp32 (T x 96)
    u16*   dbc64  = (u16*)(ws + 76832768);        //    262,144  bf16 delta cols
    u16*   dtw    = (u16*)(ws + 77094912);        //    131,072  dt_proj_w bf16
    // total 77,225,984 bytes

    transpose_w<<<dim3(32, 32, 4), 256, 0, stream>>>(conv_w, wt);
    pad_zero_k<<<48, 256, 0, stream>>>(xcp);
    xpw_k<<<1024, 256, 0, stream>>>(x_proj, xpw);
    cast_f2b_k<<<8192, 256, 0, stream>>>(in_proj, inw);
    cast_f2b_k<<<128, 256, 0, stream>>>(dt_w, dtw);
    rmsnorm_k<<<2048, 256, 0, stream>>>(x, norm_w, hy);

    gemm_bt<EPI_XZ, 1><<<dim3(16, 32), 256, 0, stream>>>(
        hy, inw, 2048, 0, 0, xcp, z_buf, nullptr, nullptr);

    cast_f2b_k<<<4096, 256, 0, stream>>>(out_w, outw);

    gemm_bt<EPI_CONV, 4><<<dim3(16, 16), 256, 0, stream>>>(
        xcp, wt, 2048, H, (long)H * H, hy, nullptr, conv_b, nullptr);

    gemm_bt<EPI_DBC, 1><<<dim3(16, 1), 256, 0, stream>>>(
        hy, xpw, 2048, 0, 0, dbc, dbc64, nullptr, nullptr);

    gemm_bt<EPI_DELTA, 1><<<dim3(16, 16), 256, 0, stream>>>(
        dbc64, dtw, 64, 0, 0, dlt, nullptr, dt_b, nullptr);

    // chunked channel-per-thread scan
    scan_part1<<<dim3(64, 8), 256, 0, stream>>>(dlt, hy, dbc, a_log, ssum, sdl);
    scan_mid<<<256, 256, 0, stream>>>(ssum, sdl, a_log);
    scan_part3<<<dim3(64, 8), 256, 0, stream>>>(dlt, hy, dbc, a_log, Dv, z_buf, ssum, y_buf);

    gemm_bt<EPI_OUT, 1><<<dim3(16, 16), 256, 0, stream>>>(
        y_buf, outw, 2048, 0, 0, out, nullptr, nullptr, x);
}

// Round 6
// 555.686 us; speedup vs baseline: 1.3253x; 1.3253x over previous
//
#include <hip/hip_runtime.h>
#include <math.h>

typedef unsigned short u16;
typedef __bf16 bf16x8 __attribute__((ext_vector_type(8)));
typedef float f32x4 __attribute__((ext_vector_type(4)));
typedef unsigned short u16x8 __attribute__((ext_vector_type(8)));
typedef unsigned short u16x4 __attribute__((ext_vector_type(4)));

#define H 2048
#define LSEQ 1024
#define LP (LSEQ+3)
#define CL 32
#define NCH 32

__device__ __forceinline__ float bf2f(u16 u) {
    union { float f; unsigned int i; } x; x.i = ((unsigned int)u) << 16; return x.f;
}
__device__ __forceinline__ u16 f2bf(float f) {
    union { float f; unsigned int i; } x; x.f = f;
    unsigned int r = x.i + 0x7fffu + ((x.i >> 16) & 1u);
    return (u16)(r >> 16);
}

__device__ __forceinline__ void gload_lds16(const void* g, void* l) {
    __builtin_amdgcn_global_load_lds((const __attribute__((address_space(1))) void*)g,
                                     (__attribute__((address_space(3))) void*)l,
                                     16, 0, 0);
}

enum { EPI_XZ = 0, EPI_DELTA = 1, EPI_ATOM = 2 };

// C[m,n] (+)= A_z[m,:] . B_z[n,:]  over this block's K-slice (z = blockIdx.z).
// BM=BN=128, BK=32, 256 threads = 4 waves, 64x64 per wave.
// LDS XOR swizzle: physical 16B-segment s of row r holds global segment s^((r>>1)&3).
template<int EPI, bool APAD>
__launch_bounds__(256)
__global__ void gemm_bt(const u16* __restrict__ A, const u16* __restrict__ B,
                        int K, long aZoff, long bZoff, int itersZ, int ldc,
                        void* __restrict__ out0, void* __restrict__ out1,
                        const float* __restrict__ bias) {
    __shared__ u16 As[128 * 32];
    __shared__ u16 Bs[128 * 32];
    const int m0 = blockIdx.x * 128;
    const int n0 = blockIdx.y * 128;
    const int z  = blockIdx.z;
    const int tid = threadIdx.x;
    const int lane = tid & 63;
    const int w = tid >> 6;
    const int wr = w >> 1, wc = w & 1;

    long abase;
    if (APAD) {
        int b = m0 >> 10, l0 = m0 & 1023;
        abase = (long)(b * LP + l0) * K;
    } else {
        abase = (long)m0 * K;
    }
    const u16* Ag = A + abase + (long)z * aZoff;
    const u16* Bg = B + (long)n0 * K + (long)z * bZoff;

    // swizzled read segment (same for A and B: row bits 1-2 come from lane&15)
    const int sw8 = ((((lane & 15) >> 1) & 3) ^ (lane >> 4)) * 8;

    f32x4 acc[4][4];
#pragma unroll
    for (int i = 0; i < 4; i++)
#pragma unroll
        for (int j = 0; j < 4; j++) acc[i][j] = (f32x4){0.f, 0.f, 0.f, 0.f};

    for (int kt = 0; kt < itersZ; ++kt) {
        const int k0 = kt * 32;
        __syncthreads();
#pragma unroll
        for (int j = 0; j < 2; j++) {
            const int idx = j * 256 + tid;
            const int r = idx >> 2;
            const int segG = ((idx & 3) ^ ((r >> 1) & 3)) * 8;
            gload_lds16(Ag + (long)r * K + k0 + segG, &As[idx * 8]);
            gload_lds16(Bg + (long)r * K + k0 + segG, &Bs[idx * 8]);
        }
        __syncthreads();
        bf16x8 af[4], bfr[4];
#pragma unroll
        for (int i = 0; i < 4; i++) {
            const int row = wr * 64 + i * 16 + (lane & 15);
            af[i] = *(const bf16x8*)&As[row * 32 + sw8];
        }
#pragma unroll
        for (int j = 0; j < 4; j++) {
            const int row = wc * 64 + j * 16 + (lane & 15);
            bfr[j] = *(const bf16x8*)&Bs[row * 32 + sw8];
        }
#pragma unroll
        for (int i = 0; i < 4; i++)
#pragma unroll
            for (int j = 0; j < 4; j++)
                acc[i][j] = __builtin_amdgcn_mfma_f32_16x16x32_bf16(af[i], bfr[j], acc[i][j], 0, 0, 0);
    }

#pragma unroll
    for (int i = 0; i < 4; i++) {
#pragma unroll
        for (int j = 0; j < 4; j++) {
#pragma unroll
            for (int r = 0; r < 4; r++) {
                const int m = m0 + wr * 64 + i * 16 + ((lane >> 4) << 2) + r;
                const int n = n0 + wc * 64 + j * 16 + (lane & 15);
                float v = acc[i][j][r];
                if constexpr (EPI == EPI_XZ) {
                    const int b = m >> 10, l = m & 1023;
                    if (n < H) ((u16*)out0)[((long)(b * LP + l + 3)) * H + n] = f2bf(v);
                    else       ((u16*)out1)[(long)m * H + (n - H)] = f2bf(v);
                } else if constexpr (EPI == EPI_DELTA) {
                    v += bias[n];
                    v = (v > 20.f) ? v : log1pf(expf(v));   // softplus
                    ((float*)out0)[(long)m * H + n] = v;
                } else {
                    atomicAdd(&((float*)out0)[(long)m * ldc + n], v);
                }
            }
        }
    }
}

__global__ void zero_k(float* __restrict__ p) {
    const long i = ((long)blockIdx.x * 256 + threadIdx.x) * 4;
    *(f32x4*)(p + i) = (f32x4){0.f, 0.f, 0.f, 0.f};
}

// conv finalize: bias + silu, fp32 partial -> bf16 xcc
__global__ void fin_conv_k(const float* __restrict__ pacc, const float* __restrict__ bias,
                           u16* __restrict__ xcc) {
    const long i = ((long)blockIdx.x * 256 + threadIdx.x) * 4;
    f32x4 v = *(const f32x4*)(pacc + i);
    const int n = (int)(i & 2047);
    f32x4 bv = *(const f32x4*)(bias + n);
    u16x4 o;
#pragma unroll
    for (int j = 0; j < 4; j++) {
        float t = v[j] + bv[j];
        o[j] = f2bf(t / (1.f + expf(-t)));
    }
    *(u16x4*)(xcc + i) = o;
}

// dbc finalize: fp32 (T x 128) partial -> dbc fp32 (T x 96) + dbc64 bf16 (T x 64)
__global__ void fin_dbc_k(const float* __restrict__ pacc, float* __restrict__ dbc,
                          u16* __restrict__ dbc64) {
    const int i = blockIdx.x * 256 + threadIdx.x;   // T*128
    const int m = i >> 7, n = i & 127;
    const float v = pacc[i];
    if (n < 96) dbc[m * 96 + n] = v;
    if (n < 64) dbc64[m * 64 + n] = f2bf(v);
}

// out finalize: partial + residual x -> fp32 out
__global__ void fin_out_k(const float* __restrict__ pacc, const float* __restrict__ x,
                          float* __restrict__ out) {
    const long i = ((long)blockIdx.x * 256 + threadIdx.x) * 4;
    f32x4 v = *(const f32x4*)(pacc + i);
    f32x4 xv = *(const f32x4*)(x + i);
#pragma unroll
    for (int j = 0; j < 4; j++) v[j] += xv[j];
    *(f32x4*)(out + i) = v;
}

// conv_w (tap,i,o) fp32 -> Wt (tap,o,i) bf16
__global__ void transpose_w(const float* __restrict__ in, u16* __restrict__ out) {
    __shared__ u16 s[64][72];
    const int tap = blockIdx.z;
    const long base = (long)tap * H * H;
    const int i0 = blockIdx.x * 64, o0 = blockIdx.y * 64;
    const int r = threadIdx.x >> 3;
    const int c = (threadIdx.x & 7) * 8;
#pragma unroll
    for (int rr = r; rr < 64; rr += 32) {
        f32x4 a = *(const f32x4*)&in[base + (long)(i0 + rr) * H + o0 + c];
        f32x4 b = *(const f32x4*)&in[base + (long)(i0 + rr) * H + o0 + c + 4];
#pragma unroll
        for (int j = 0; j < 4; j++) { s[rr][c + j] = f2bf(a[j]); s[rr][c + 4 + j] = f2bf(b[j]); }
    }
    __syncthreads();
#pragma unroll
    for (int rr = r; rr < 64; rr += 32) {
        u16x8 v;
#pragma unroll
        for (int j = 0; j < 8; j++) v[j] = s[c + j][rr];
        *(u16x8*)&out[base + (long)(o0 + rr) * H + i0 + c] = v;
    }
}

__global__ void cast_f2b_k(const float* __restrict__ in, u16* __restrict__ out) {
    const long i = ((long)blockIdx.x * 256 + threadIdx.x) * 4;
    f32x4 v = *(const f32x4*)(in + i);
    u16x4 o;
#pragma unroll
    for (int j = 0; j < 4; j++) o[j] = f2bf(v[j]);
    *(u16x4*)(out + i) = o;
}

__global__ void pad_zero_k(u16* __restrict__ xcp) {
    const int i = blockIdx.x * 256 + threadIdx.x;   // 2*3*H total
    const int b = i / (3 * H);
    const int r = i - b * 3 * H;
    xcp[(long)b * LP * H + r] = 0;
}

__global__ void xpw_k(const float* __restrict__ xp, u16* __restrict__ out) {
    const int i = blockIdx.x * 256 + threadIdx.x;   // 128*H
    const int r = i >> 11;
    out[i] = (r < 96) ? f2bf(xp[i]) : (u16)0;
}

__global__ void rmsnorm_k(const float* __restrict__ x, const float* __restrict__ w, u16* __restrict__ h) {
    const long base = (long)blockIdx.x * H;
    const int tid = threadIdx.x;
    f32x4 a = *(const f32x4*)&x[base + tid * 8];
    f32x4 b = *(const f32x4*)&x[base + tid * 8 + 4];
    float f[8];
    float ss = 0.f;
#pragma unroll
    for (int j = 0; j < 4; j++) { f[j] = a[j]; f[4 + j] = b[j]; }
#pragma unroll
    for (int j = 0; j < 8; j++) ss += f[j] * f[j];
#pragma unroll
    for (int m = 32; m > 0; m >>= 1) ss += __shfl_down(ss, m);
    __shared__ float red[4];
    if ((tid & 63) == 0) red[tid >> 6] = ss;
    __syncthreads();
    ss = red[0] + red[1] + red[2] + red[3];
    const float scale = rsqrtf(ss * (1.f / H) + 1e-5f);
    f32x4 wa = *(const f32x4*)&w[tid * 8];
    f32x4 wb = *(const f32x4*)&w[tid * 8 + 4];
    u16x8 o;
#pragma unroll
    for (int j = 0; j < 4; j++) { o[j] = f2bf(f[j] * scale * wa[j]); o[4 + j] = f2bf(f[4 + j] * scale * wb[j]); }
    *(u16x8*)&h[base + tid * 8] = o;
}

// ---------- chunked scan, channel-per-thread (round-5 structure) ----------
__launch_bounds__(256)
__global__ void scan_part1(const float* __restrict__ delta, const u16* __restrict__ xc,
                           const float* __restrict__ dbc, const float* __restrict__ alog,
                           u16* __restrict__ ssum, float* __restrict__ sdl_buf) {
    __shared__ float sB[CL * 16];
    const int tid = threadIdx.x;
    const int bc = blockIdx.x;          // b*NCH + c
    const int b = bc >> 5, c = bc & 31;
    const int h = blockIdx.y * 256 + tid;
    const long tok0 = (long)b * LSEQ + c * CL;
    {
        const int r = tid >> 4, n = tid & 15;
        sB[tid] = dbc[(tok0 + r) * 96 + 64 + n];
        sB[tid + 256] = dbc[(tok0 + r + 16) * 96 + 64 + n];
    }
    __syncthreads();
    float An[16]; bool fast = true;
#pragma unroll
    for (int n = 0; n < 16; n++) {
        An[n] = -expf(alog[h * 16 + n]);
        fast = fast && (fabsf(An[n] + (float)(n + 1)) < 1e-3f * (n + 1));
    }
    float s[16];
#pragma unroll
    for (int n = 0; n < 16; n++) s[n] = 0.f;
    float sdl = 0.f;
    const float* dptr = delta + tok0 * H + h;
    const u16* xptr = xc + tok0 * H + h;
    float dl = dptr[0], xv = bf2f(xptr[0]);
    if (fast) {
        for (int j = 0; j < CL; j++) {
            const long jn = (j < CL - 1) ? (long)(j + 1) * H : (long)j * H;
            const float dl2 = dptr[jn]; const float xv2 = bf2f(xptr[jn]);
            sdl += dl;
            const float e1 = expf(-dl);
            const float u = dl * xv;
            const f32x4* Bv = (const f32x4*)&sB[j * 16];
            float ep = 1.f;
#pragma unroll
            for (int q = 0; q < 4; q++) {
                const f32x4 bb = Bv[q];
#pragma unroll
                for (int k = 0; k < 4; k++) { ep *= e1; s[q*4+k] = ep * s[q*4+k] + u * bb[k]; }
            }
            dl = dl2; xv = xv2;
        }
    } else {
        for (int j = 0; j < CL; j++) {
            const long jn = (j < CL - 1) ? (long)(j + 1) * H : (long)j * H;
            const float dl2 = dptr[jn]; const float xv2 = bf2f(xptr[jn]);
            sdl += dl;
            const float u = dl * xv;
            const f32x4* Bv = (const f32x4*)&sB[j * 16];
#pragma unroll
            for (int q = 0; q < 4; q++) {
                const f32x4 bb = Bv[q];
#pragma unroll
                for (int k = 0; k < 4; k++) { const float e = expf(dl * An[q*4+k]); s[q*4+k] = e * s[q*4+k] + u * bb[k]; }
            }
            dl = dl2; xv = xv2;
        }
    }
    u16x8 o0, o1;
#pragma unroll
    for (int n = 0; n < 8; n++) { o0[n] = f2bf(s[n]); o1[n] = f2bf(s[8 + n]); }
    const long sb = ((long)bc * H + h) * 16;
    *(u16x8*)&ssum[sb] = o0;
    *(u16x8*)&ssum[sb + 8] = o1;
    sdl_buf[(long)bc * H + h] = sdl;
}

__global__ void scan_mid(u16* __restrict__ ssum, const float* __restrict__ sdl_buf,
                         const float* __restrict__ alog) {
    const int tg = blockIdx.x * 256 + threadIdx.x;
    const int b = tg >> 15;
    const int rest = tg & 32767;
    const int h = rest >> 4, n = rest & 15;
    const float An = -expf(alog[h * 16 + n]);
    float S = 0.f;
    for (int c = 0; c < NCH; c++) {
        const long base = (long)(b * NCH + c) * H + h;
        const float a = expf(An * sdl_buf[base]);
        const long si = base * 16 + n;
        const float sloc = bf2f(ssum[si]);
        ssum[si] = f2bf(S);
        S = a * S + sloc;
    }
}

__launch_bounds__(256)
__global__ void scan_part3(const float* __restrict__ delta, const u16* __restrict__ xc,
                           const float* __restrict__ dbc, const float* __restrict__ alog,
                           const float* __restrict__ dvec, const u16* __restrict__ z,
                           const u16* __restrict__ ssum, u16* __restrict__ ybuf) {
    __shared__ float sB[CL * 16];
    __shared__ float sC[CL * 16];
    const int tid = threadIdx.x;
    const int bc = blockIdx.x;
    const int b = bc >> 5, c = bc & 31;
    const int h = blockIdx.y * 256 + tid;
    const long tok0 = (long)b * LSEQ + c * CL;
    {
        const int r = tid >> 4, n = tid & 15;
        sB[tid]       = dbc[(tok0 + r) * 96 + 64 + n];
        sB[tid + 256] = dbc[(tok0 + r + 16) * 96 + 64 + n];
        sC[tid]       = dbc[(tok0 + r) * 96 + 80 + n];
        sC[tid + 256] = dbc[(tok0 + r + 16) * 96 + 80 + n];
    }
    __syncthreads();
    float An[16]; bool fast = true;
#pragma unroll
    for (int n = 0; n < 16; n++) {
        An[n] = -expf(alog[h * 16 + n]);
        fast = fast && (fabsf(An[n] + (float)(n + 1)) < 1e-3f * (n + 1));
    }
    float s[16];
    {
        const long sb = ((long)bc * H + h) * 16;
        u16x8 i0 = *(const u16x8*)&ssum[sb];
        u16x8 i1 = *(const u16x8*)&ssum[sb + 8];
#pragma unroll
        for (int n = 0; n < 8; n++) { s[n] = bf2f(i0[n]); s[8 + n] = bf2f(i1[n]); }
    }
    const float Dh = dvec[h];
    const float* dptr = delta + tok0 * H + h;
    const u16* xptr = xc + tok0 * H + h;
    const u16* zptr = z + tok0 * H + h;
    u16* yptr = ybuf + tok0 * H + h;
    float dl = dptr[0], xv = bf2f(xptr[0]), zf = bf2f(zptr[0]);
    if (fast) {
        for (int j = 0; j < CL; j++) {
            const long jn = (j < CL - 1) ? (long)(j + 1) * H : (long)j * H;
            const float dl2 = dptr[jn]; const float xv2 = bf2f(xptr[jn]); const float zf2 = bf2f(zptr[jn]);
            const float e1 = expf(-dl);
            const float u = dl * xv;
            const f32x4* Bv = (const f32x4*)&sB[j * 16];
            const f32x4* Cv = (const f32x4*)&sC[j * 16];
            float ep = 1.f, y = 0.f;
#pragma unroll
            for (int q = 0; q < 4; q++) {
                const f32x4 bb = Bv[q], cc = Cv[q];
#pragma unroll
                for (int k = 0; k < 4; k++) {
                    ep *= e1;
                    s[q*4+k] = ep * s[q*4+k] + u * bb[k];
                    y += s[q*4+k] * cc[k];
                }
            }
            y += Dh * xv;
            const float g = zf / (1.f + expf(-zf));
            yptr[(long)j * H] = f2bf(y * g);
            dl = dl2; xv = xv2; zf = zf2;
        }
    } else {
        for (int j = 0; j < CL; j++) {
            const long jn = (j < CL - 1) ? (long)(j + 1) * H : (long)j * H;
            const float dl2 = dptr[jn]; const float xv2 = bf2f(xptr[jn]); const float zf2 = bf2f(zptr[jn]);
            const float u = dl * xv;
            const f32x4* Bv = (const f32x4*)&sB[j * 16];
            const f32x4* Cv = (const f32x4*)&sC[j * 16];
            float y = 0.f;
#pragma unroll
            for (int q = 0; q < 4; q++) {
                const f32x4 bb = Bv[q], cc = Cv[q];
#pragma unroll
                for (int k = 0; k < 4; k++) {
                    const float e = expf(dl * An[q*4+k]);
                    s[q*4+k] = e * s[q*4+k] + u * bb[k];
                    y += s[q*4+k] * cc[k];
                }
            }
            y += Dh * xv;
            const float g = zf / (1.f + expf(-zf));
            yptr[(long)j * H] = f2bf(y * g);
            dl = dl2; xv = xv2; zf = zf2;
        }
    }
}

extern "C" void kernel_launch(void* const* d_in, const int* in_sizes, int n_in,
                              void* d_out, int out_size, void* d_ws, size_t ws_size,
                              hipStream_t stream) {
    const float* x       = (const float*)d_in[0];
    const float* norm_w  = (const float*)d_in[1];
    const float* in_proj = (const float*)d_in[2];
    const float* conv_w  = (const float*)d_in[3];
    const float* conv_b  = (const float*)d_in[4];
    const float* x_proj  = (const float*)d_in[5];
    const float* dt_w    = (const float*)d_in[6];
    const float* dt_b    = (const float*)d_in[7];
    const float* a_log   = (const float*)d_in[8];
    const float* Dv      = (const float*)d_in[9];
    const float* out_w   = (const float*)d_in[10];
    float* out = (float*)d_out;

    char* ws = (char*)d_ws;
    u16*   xcp    = (u16*)(ws);                   //  8,413,184  padded conv input (bf16)
    u16*   hy     = (u16*)(ws + 8413184);         //  8,388,608  h -> xcc
    u16*   z_buf  = (u16*)(ws + 16801792);        //  8,388,608
    u16*   wt     = (u16*)(ws + 25190400);        // 33,554,432  conv_w^T (dead after conv)
    float* dlt    = (float*)(ws + 25190400);      // 16,777,216  aliases wt
    u16*   y_buf  = (u16*)(ws + 41967616);        //  8,388,608  aliases wt
    u16*   ssum   = (u16*)(ws + 50356224);        //  8,388,608  aliases wt
    u16*   inw    = (u16*)(ws + 58744832);        // 16,777,216  in_proj bf16 (dead after XZ)
    float* pacc   = (float*)(ws + 58744832);      // 16,777,216  split-K partials (aliases inw)
    u16*   xpw    = (u16*)(ws + 75522048);        //    524,288
    float* dbc    = (float*)(ws + 76046336);      //    786,432
    u16*   dbc64  = (u16*)(ws + 76832768);        //    262,144
    u16*   dtw    = (u16*)(ws + 77094912);        //    131,072
    float* sdl    = (float*)(ws + 77225984);      //    524,288
    u16*   outw   = (u16*)(ws + 77750272);        //  8,388,608
    // total 86,138,880 bytes

    transpose_w<<<dim3(32, 32, 4), 256, 0, stream>>>(conv_w, wt);
    pad_zero_k<<<48, 256, 0, stream>>>(xcp);
    xpw_k<<<1024, 256, 0, stream>>>(x_proj, xpw);
    cast_f2b_k<<<8192, 256, 0, stream>>>(in_proj, inw);
    cast_f2b_k<<<128, 256, 0, stream>>>(dt_w, dtw);
    rmsnorm_k<<<2048, 256, 0, stream>>>(x, norm_w, hy);

    // xz = h @ in_proj_w.T (direct epilogue: xc padded + z)
    gemm_bt<EPI_XZ, false><<<dim3(16, 32, 1), 256, 0, stream>>>(
        hy, inw, 2048, 0, 0, 64, 0, xcp, z_buf, nullptr);

    cast_f2b_k<<<4096, 256, 0, stream>>>(out_w, outw);

    // conv: 4-way tap split into fp32 partials, then bias+silu finalize
    zero_k<<<4096, 256, 0, stream>>>(pacc);
    gemm_bt<EPI_ATOM, true><<<dim3(16, 16, 4), 256, 0, stream>>>(
        xcp, wt, 2048, H, (long)H * H, 64, 2048, pacc, nullptr, nullptr);
    fin_conv_k<<<4096, 256, 0, stream>>>(pacc, conv_b, hy);

    // dBC: 8-way K split
    zero_k<<<256, 256, 0, stream>>>(pacc);
    gemm_bt<EPI_ATOM, false><<<dim3(16, 1, 8), 256, 0, stream>>>(
        hy, xpw, 2048, 256, 256, 8, 128, pacc, nullptr, nullptr);
    fin_dbc_k<<<1024, 256, 0, stream>>>(pacc, dbc, dbc64);

    // delta = softplus(dbc64 @ dt_proj_w.T + dt_b), direct
    gemm_bt<EPI_DELTA, false><<<dim3(16, 16, 1), 256, 0, stream>>>(
        dbc64, dtw, 64, 0, 0, 2, 0, dlt, nullptr, dt_b);

    // chunked channel-per-thread scan (+ fused gate)
    scan_part1<<<dim3(64, 8), 256, 0, stream>>>(dlt, hy, dbc, a_log, ssum, sdl);
    scan_mid<<<256, 256, 0, stream>>>(ssum, sdl, a_log);
    scan_part3<<<dim3(64, 8), 256, 0, stream>>>(dlt, hy, dbc, a_log, Dv, z_buf, ssum, y_buf);

    // out = x + yg @ out_proj_w.T : 4-way K split + residual finalize
    zero_k<<<4096, 256, 0, stream>>>(pacc);
    gemm_bt<EPI_ATOM, false><<<dim3(16, 16, 4), 256, 0, stream>>>(
        y_buf, outw, 2048, 512, 512, 16, 2048, pacc, nullptr, nullptr);
    fin_out_k<<<4096, 256, 0, stream>>>(pacc, x, out);
}